// Round 8
// baseline (70.625 us; speedup 1.0000x reference)
//
#include <hip/hip_runtime.h>

// DecisionTreePolicy — complete binary tree, depth 15 (32767 nodes).
// Internal 0..16382 (children 2i+1/2i+2), leaves 16383..32766 -> exactly 14
// decisions from root; out[b] = leaf_logits[leaf(b)].
//
// R4 68.5 / R7 67.2: single-stream waves -> the epilogue's gather-dependent
// store forces the compiler's vmcnt wait to DRAIN the prefetch every tile
// (in-order vmcnt retirement). R8: producer/consumer wave split — vmcnt is
// per-wave, so producer waves (obs loads only) keep a never-drained depth-2
// pipeline while consumer waves absorb the gather waits. Also: XOR-swizzled
// obs tile (converged-node reads were 32-way bank conflicts) and paired-
// children tree layout (b64 thr-pair + u16 feat-pair = 3 LDS insts/level).

#define N_PAIR   8191      // parents whose children are internal: nodes 0..8190
#define N_FEAT   256
#define N_ACT    64
#define BATCH    262144
#define BLOCK    512       // waves 0-3 producers, waves 4-7 consumers
#define GRID     256
#define ROWS_PB  (BATCH / GRID)     // 1024 rows per block
#define TROWS    32                 // rows per tile (32 KB)
#define NTILES   (ROWS_PB / TROWS)  // 32
#define DEPTH    14
#define PFN      8                  // f32x4 per producer thread per tile
#define TSLOTS   (TROWS * N_FEAT / 4)  // 2048 f32x4 per tile

typedef float f32x4 __attribute__((ext_vector_type(4)));

__global__ __launch_bounds__(BLOCK, 1) void tree_policy_kernel(
    const float* __restrict__ obs,          // [BATCH][N_FEAT]
    const int*   __restrict__ features,     // [N_NODES]
    const float* __restrict__ thresholds,   // [N_NODES]
    const float* __restrict__ leaf_logits,  // [N_NODES][N_ACT]
    float*       __restrict__ out)          // [BATCH][N_ACT]
{
    __shared__ float2         sthr2 [N_PAIR];      // {thr[2n+1], thr[2n+2]} 65528 B
    __shared__ unsigned short sfeat2[N_PAIR];      // feat[2n+1] | feat[2n+2]<<8, 16382 B
    __shared__ __align__(16) f32x4 buf[2][TSLOTS]; // 2 x 32 KB obs tiles (swizzled)
    // total ~147.4 KB -> 1 block/CU, 8 waves = 1 producer + 1 consumer per SIMD

    const int  tid  = threadIdx.x;
    const bool isP  = tid < 256;               // wave-uniform role split
    const int  lane = tid & 63;
    const long rowBase = (long)blockIdx.x * ROWS_PB;
    const f32x4* gsrc = (const f32x4*)(obs + rowBase * N_FEAT);

    float thr_root = 0.f; int feat_root = 0;
    f32x4 pfA[PFN], pfB[PFN];                  // producer-only; dead regs for consumers

    // ---------------- prologue ----------------
    if (isP) {
        const int g = tid;                     // 0..255
#pragma unroll
        for (int k = 0; k < PFN; ++k)          // tile 0 -> pfA
            pfA[k] = __builtin_nontemporal_load(&gsrc[0 * TSLOTS + k * 256 + g]);
#pragma unroll
        for (int k = 0; k < PFN; ++k)          // tile 1 -> pfB
            pfB[k] = __builtin_nontemporal_load(&gsrc[1 * TSLOTS + k * 256 + g]);
        asm volatile("s_waitcnt vmcnt(8)" ::: "memory");   // tile 0 landed
#pragma unroll
        for (int k = 0; k < PFN; ++k) {        // write tile 0, swizzled
            const int s = k * 256 + g, row = s >> 6, c4 = s & 63;
            buf[0][row * 64 + (c4 ^ (row & 7))] = pfA[k];
        }
#pragma unroll
        for (int k = 0; k < PFN; ++k)          // re-issue pfA for tile 2
            pfA[k] = __builtin_nontemporal_load(&gsrc[2 * TSLOTS + k * 256 + g]);
        asm volatile("s_waitcnt lgkmcnt(0)" ::: "memory");
    } else {
        const int g = tid - 256;               // 0..255: stage tree (paired layout)
        for (int i = g; i < N_PAIR; i += 256) {
            sthr2[i]  = make_float2(thresholds[2 * i + 1], thresholds[2 * i + 2]);
            sfeat2[i] = (unsigned short)((features[2 * i + 1] & 255) |
                                         ((features[2 * i + 2] & 255) << 8));
        }
        thr_root  = thresholds[0];
        feat_root = features[0];
        asm volatile("s_waitcnt lgkmcnt(0)" ::: "memory");
    }
    __builtin_amdgcn_s_barrier();              // tree + tile 0 visible
    __builtin_amdgcn_sched_barrier(0);

    // ---------------- producer body: stage tile k+1, re-issue for k+3 ----------------
    auto prod = [&](int k, f32x4 (&pf)[PFN]) {
        if (k < NTILES - 1) {
            const int g = tid;
            // outstanding (oldest first): loads(k+1)=pf, loads(k+2)=other group.
            if (k == NTILES - 2) asm volatile("s_waitcnt vmcnt(0)" ::: "memory");
            else                 asm volatile("s_waitcnt vmcnt(8)" ::: "memory");
            __builtin_amdgcn_sched_barrier(0);
            const int tp = (k + 1) & 1;
#pragma unroll
            for (int kk = 0; kk < PFN; ++kk) {
                const int s = kk * 256 + g, row = s >> 6, c4 = s & 63;
                buf[tp][row * 64 + (c4 ^ (row & 7))] = pf[kk];
            }
            if (k + 3 <= NTILES - 1) {         // re-issue same group for tile k+3
#pragma unroll
                for (int kk = 0; kk < PFN; ++kk)
                    pf[kk] = __builtin_nontemporal_load(
                        &gsrc[(long)(k + 3) * TSLOTS + kk * 256 + g]);
            }
            asm volatile("s_waitcnt lgkmcnt(0)" ::: "memory");
        }
    };

    // ---------------- consumer body: traverse tile k + epilogue ----------------
    auto cons = [&](int k) {
        const int g = tid - 256;
        const float* bufc = (const float*)&buf[k & 1][0];
        const int r = lane & 31;               // each lane owns row r (2x in-wave dup)
        int node = 0; float tcur = thr_root; int fcur = feat_root;
#pragma unroll
        for (int d = 0; d < DEPTH - 1; ++d) {
            const float x = bufc[(r * 64 + ((fcur >> 2) ^ (r & 7))) * 4 + (fcur & 3)];
            const float2   tch = sthr2[node];  // both children's thr: one ds_read_b64
            const unsigned fp  = sfeat2[node]; // both children's feat: one ds_read_u16
            const bool L = (x <= tcur);        // reference NaN semantics
            node = 2 * node + (L ? 1 : 2);
            tcur = L ? tch.x : tch.y;
            fcur = (int)(L ? (fp & 255u) : (fp >> 8));
        }
        {   // last decision peeled: children are leaves
            const float x = bufc[(r * 64 + ((fcur >> 2) ^ (r & 7))) * 4 + (fcur & 3)];
            node = 2 * node + ((x <= tcur) ? 1 : 2);
        }
        // epilogue: 32 rows x 16 chunks = 512 f32x4 over 256 consumer threads
        const long outRow0 = rowBase + (long)k * TROWS;
#pragma unroll
        for (int jj = 0; jj < 2; ++jj) {
            const int fid = jj * 256 + g;
            const int rr = fid >> 4, chunk = fid & 15;
            const int leaf = __shfl(node, rr, 64);   // lane rr holds row rr
            const f32x4 v = *(const f32x4*)(leaf_logits + (size_t)leaf * N_ACT + chunk * 4);
            __builtin_nontemporal_store(v, (f32x4*)(out + (outRow0 + rr) * N_ACT + chunk * 4));
        }
    };

    // ---------------- main loop: unrolled x2 for static pfA/pfB roles ----------------
    for (int kk = 0; kk < NTILES; kk += 2) {
        if (isP) prod(kk, pfB); else cons(kk);        // even k stages odd tile (pfB)
        __builtin_amdgcn_s_barrier();
        __builtin_amdgcn_sched_barrier(0);
        if (isP) prod(kk + 1, pfA); else cons(kk + 1); // odd k stages even tile (pfA)
        __builtin_amdgcn_s_barrier();
        __builtin_amdgcn_sched_barrier(0);
    }
}

extern "C" void kernel_launch(void* const* d_in, const int* in_sizes, int n_in,
                              void* d_out, int out_size, void* d_ws, size_t ws_size,
                              hipStream_t stream) {
    const float* obs         = (const float*)d_in[0];
    const int*   features    = (const int*)  d_in[1];
    const float* thresholds  = (const float*)d_in[2];
    // d_in[3]/d_in[4] (children) unused: tree is complete by construction.
    const float* leaf_logits = (const float*)d_in[5];
    float*       out         = (float*)d_out;

    tree_policy_kernel<<<dim3(GRID), dim3(BLOCK), 0, stream>>>(
        obs, features, thresholds, leaf_logits, out);
}

// Round 9
// 68.913 us; speedup vs baseline: 1.0248x; 1.0248x over previous
//
#include <hip/hip_runtime.h>

// DecisionTreePolicy — complete binary tree, depth 15 (32767 nodes).
// Internal 0..16382 (children 2i+1/2i+2), leaves 16383..32766 -> exactly 14
// decisions from root; out[b] = leaf_logits[leaf(b)].
//
// History: R1/R2 scattered gathers 84us (470MB HBM). R4 LDS-streaming 68.5us.
// R5 wave-redundancy 78us. R6 vmcnt(0)/tile 80us. R7 depth-2 counted-vmcnt
// 67.2us (best). R8 producer/consumer split 70.6us -> staging drain is NOT
// the gap; effective BW ~5.1 TB/s says the read pipe is Little's-law starved
// (depth-2 dips to 32KB in flight after each wait; need ~40-60KB sustained).
// R9: depth-4 register pipeline (pfA-D, 128KB/CU in flight, waits are
// vmcnt(28) -- never drained), two raw barriers per half (fixes R7's latent
// write-vs-read race), otherwise identical traversal/epilogue.

#define N_INTERN  16383
#define N_FEAT    256
#define N_ACT     64
#define BATCH     262144
#define BLOCK     256
#define GRID      256
#define ROWS_PB   (BATCH / GRID)      // 1024 rows per block
#define HROWS     32                  // rows per half-tile (32 KB)
#define HALVES    (ROWS_PB / HROWS)   // 32
#define DEPTH     14
#define PFN       8                   // f32x4 per thread per half-tile
#define TSLOTS    (HROWS * N_FEAT / 4)  // 2048 f32x4 per half-tile

typedef float f32x4 __attribute__((ext_vector_type(4)));

__global__ __launch_bounds__(BLOCK, 1) void tree_policy_kernel(
    const float* __restrict__ obs,          // [BATCH][N_FEAT]
    const int*   __restrict__ features,     // [N_NODES]
    const float* __restrict__ thresholds,   // [N_NODES]
    const float* __restrict__ leaf_logits,  // [N_NODES][N_ACT]
    float*       __restrict__ out)          // [BATCH][N_ACT]
{
    __shared__ float         sthr [N_INTERN];        // 64 KB
    __shared__ unsigned char sfeat[N_INTERN];        // 16 KB
    __shared__ __align__(16) f32x4 buf[2][TSLOTS];   // 2 x 32 KB -> 143.6 KB total

    const int tid  = threadIdx.x;
    const int lane = tid & 63;
    const long rowBase = (long)blockIdx.x * ROWS_PB;
    const f32x4* gsrc = (const f32x4*)(obs + rowBase * N_FEAT);

    // ---- tree -> LDS (compiler manages its own waits here) ----
    for (int i = tid; i < N_INTERN; i += BLOCK) {
        sthr[i]  = thresholds[i];
        sfeat[i] = (unsigned char)features[i];
    }
    const float thr_root  = thresholds[0];
    const int   feat_root = features[0];

    // ---- prologue: fill the depth-4 pipe (halves 0..3) ----
    f32x4 pfA[PFN], pfB[PFN], pfC[PFN], pfD[PFN];
#pragma unroll
    for (int k = 0; k < PFN; ++k)
        pfA[k] = __builtin_nontemporal_load(&gsrc[0 * TSLOTS + k * BLOCK + tid]);
#pragma unroll
    for (int k = 0; k < PFN; ++k)
        pfB[k] = __builtin_nontemporal_load(&gsrc[1 * TSLOTS + k * BLOCK + tid]);
#pragma unroll
    for (int k = 0; k < PFN; ++k)
        pfC[k] = __builtin_nontemporal_load(&gsrc[2 * TSLOTS + k * BLOCK + tid]);
#pragma unroll
    for (int k = 0; k < PFN; ++k)
        pfD[k] = __builtin_nontemporal_load(&gsrc[3 * TSLOTS + k * BLOCK + tid]);

    auto body = [&](int h, f32x4 (&pf)[PFN]) {
        // pre-barrier: all waves done READING buf[h&1] (tile h-2) -> safe to write.
        __builtin_amdgcn_s_barrier();
        __builtin_amdgcn_sched_barrier(0);
        // counted wait for loads(h); younger = loads(h+1..h+3) + 4 epilogue ops.
        // In-order vmcnt retirement => reaching the count proves loads(h) landed.
        if (h == 0)        asm volatile("s_waitcnt vmcnt(24)" ::: "memory");
        else if (h <= 28)  asm volatile("s_waitcnt vmcnt(28)" ::: "memory");
        else if (h == 29)  asm volatile("s_waitcnt vmcnt(20)" ::: "memory");
        else if (h == 30)  asm volatile("s_waitcnt vmcnt(12)" ::: "memory");
        else               asm volatile("s_waitcnt vmcnt(4)"  ::: "memory");
        __builtin_amdgcn_sched_barrier(0);
        // regs -> LDS (linear layout)
#pragma unroll
        for (int k = 0; k < PFN; ++k)
            buf[h & 1][k * BLOCK + tid] = pf[k];
        // re-issue this register group for half h+4 (keeps 128KB/CU in flight)
        if (h <= HALVES - 5) {
#pragma unroll
            for (int k = 0; k < PFN; ++k)
                pf[k] = __builtin_nontemporal_load(
                    &gsrc[(long)(h + 4) * TSLOTS + k * BLOCK + tid]);
        }
        asm volatile("s_waitcnt lgkmcnt(0)" ::: "memory");  // my ds_writes committed
        __builtin_amdgcn_s_barrier();                        // buf[h&1] visible to all
        __builtin_amdgcn_sched_barrier(0);

        // ---- traversal: row = lane&31; child-prefetch form (obs lookup with
        //      fcur-from-register runs parallel to children's thr/feat reads
        //      -> one LDS round-trip per level) ----
        const float* myrow = (const float*)&buf[h & 1][0] + (lane & 31) * N_FEAT;
        int   node = 0;
        float tcur = thr_root;
        int   fcur = feat_root;
#pragma unroll
        for (int d = 0; d < DEPTH - 1; ++d) {
            const float x   = myrow[fcur];
            const int   c   = 2 * node + 1;
            const float tl  = sthr[c];
            const float trr = sthr[c + 1];
            const int   fl  = sfeat[c];
            const int   fr  = sfeat[c + 1];
            const bool  L   = (x <= tcur);          // reference NaN semantics
            node = L ? c : c + 1;
            tcur = L ? tl : trr;
            fcur = L ? fl : fr;
        }
        {   // last decision peeled: children are leaves (no LDS entries)
            const float x = myrow[fcur];
            node = 2 * node + ((x <= tcur) ? 1 : 2);
        }
        // node = leaf id in [16383, 32766]

        // ---- epilogue: 32 rows x 16 chunks = 512 f32x4, 2 per thread ----
        const long outRow0 = rowBase + (long)h * HROWS;
#pragma unroll
        for (int j = 0; j < 2; ++j) {
            const int fid   = j * BLOCK + tid;
            const int r     = fid >> 4;
            const int chunk = fid & 15;
            const int leaf  = __shfl(node, r, 64);
            const f32x4 v   = *(const f32x4*)(leaf_logits + (size_t)leaf * N_ACT + chunk * 4);
            __builtin_nontemporal_store(v, (f32x4*)(out + (outRow0 + r) * N_ACT + chunk * 4));
        }
    };

    for (int hh = 0; hh < HALVES; hh += 4) {
        body(hh + 0, pfA);
        body(hh + 1, pfB);
        body(hh + 2, pfC);
        body(hh + 3, pfD);
    }
}

extern "C" void kernel_launch(void* const* d_in, const int* in_sizes, int n_in,
                              void* d_out, int out_size, void* d_ws, size_t ws_size,
                              hipStream_t stream) {
    const float* obs         = (const float*)d_in[0];
    const int*   features    = (const int*)  d_in[1];
    const float* thresholds  = (const float*)d_in[2];
    // d_in[3]/d_in[4] (children) unused: tree is complete by construction.
    const float* leaf_logits = (const float*)d_in[5];
    float*       out         = (float*)d_out;

    tree_policy_kernel<<<dim3(GRID), dim3(BLOCK), 0, stream>>>(
        obs, features, thresholds, leaf_logits, out);
}